// Round 2
// baseline (164.912 us; speedup 1.0000x reference)
//
#include <hip/hip_runtime.h>

// change[i] (i>=1)  = ((g(i-3) - g(i+2)) / 5)^2   with g(k)=f[k] zero-padded
// change[0] = 0
// out[i] = (1 - change[i]/S)^5 * f[i],  S = sum(change)

__device__ __forceinline__ float change_term(const float* __restrict__ f, long long i, long long n) {
    if (i < 1) return 0.0f;
    float a = (i >= 3)      ? f[i - 3] : 0.0f;
    float b = (i + 2 < n)   ? f[i + 2] : 0.0f;
    float d = (a - b) * 0.2f;
    return d * d;
}

__device__ __forceinline__ float pow5(float t) {
    float t2 = t * t;
    float t4 = t2 * t2;
    return t4 * t;
}

__global__ void reduce_change_kernel(const float* __restrict__ f, int nvec, long long n,
                                     float* __restrict__ sum_out) {
    const float4* __restrict__ fv = (const float4*)f;
    int v0 = blockIdx.x * blockDim.x + threadIdx.x;
    int stride = gridDim.x * blockDim.x;
    float acc = 0.0f;
    for (int v = v0; v < nvec; v += stride) {
        if (v >= 1 && v < nvec - 1) {
            float4 p = fv[v - 1];
            float4 c = fv[v];
            float4 q = fv[v + 1];
            // element j = 4v+k: a=f[j-3], b=f[j+2]
            float d0 = (p.y - c.z) * 0.2f;
            float d1 = (p.z - c.w) * 0.2f;
            float d2 = (p.w - q.x) * 0.2f;
            float d3 = (c.x - q.y) * 0.2f;
            acc += d0 * d0 + d1 * d1 + d2 * d2 + d3 * d3;
        } else {
            long long j0 = 4LL * v;
            for (int k = 0; k < 4; ++k) acc += change_term(f, j0 + k, n);
        }
    }
    // wave (64-lane) reduction
    #pragma unroll
    for (int off = 32; off > 0; off >>= 1)
        acc += __shfl_down(acc, off, 64);
    __shared__ float smem[4];  // 256 threads / 64 lanes
    int lane = threadIdx.x & 63;
    int wave = threadIdx.x >> 6;
    if (lane == 0) smem[wave] = acc;
    __syncthreads();
    if (threadIdx.x == 0) {
        float s = smem[0] + smem[1] + smem[2] + smem[3];
        atomicAdd(sum_out, s);
    }
}

__global__ void finalize_kernel(const float* __restrict__ f, int nvec, long long n,
                                const float* __restrict__ sum_in,
                                float* __restrict__ out) {
    int v = blockIdx.x * blockDim.x + threadIdx.x;
    if (v >= nvec) return;
    float inv = 1.0f / *sum_in;
    const float4* __restrict__ fv = (const float4*)f;
    float4 o;
    if (v >= 1 && v < nvec - 1) {
        float4 p = fv[v - 1];
        float4 c = fv[v];
        float4 q = fv[v + 1];
        float d0 = (p.y - c.z) * 0.2f;
        float d1 = (p.z - c.w) * 0.2f;
        float d2 = (p.w - q.x) * 0.2f;
        float d3 = (c.x - q.y) * 0.2f;
        o.x = pow5(1.0f - d0 * d0 * inv) * c.x;
        o.y = pow5(1.0f - d1 * d1 * inv) * c.y;
        o.z = pow5(1.0f - d2 * d2 * inv) * c.z;
        o.w = pow5(1.0f - d3 * d3 * inv) * c.w;
    } else {
        long long j0 = 4LL * v;
        float r[4];
        for (int k = 0; k < 4; ++k) {
            long long j = j0 + k;
            float c = change_term(f, j, n) * inv;
            r[k] = pow5(1.0f - c) * f[j];
        }
        o.x = r[0]; o.y = r[1]; o.z = r[2]; o.w = r[3];
    }
    ((float4*)out)[v] = o;
}

extern "C" void kernel_launch(void* const* d_in, const int* in_sizes, int n_in,
                              void* d_out, int out_size, void* d_ws, size_t ws_size,
                              hipStream_t stream) {
    const float* f = (const float*)d_in[0];
    float* out = (float*)d_out;
    float* sum_ws = (float*)d_ws;
    long long n = (long long)in_sizes[0];
    int nvec = (int)(n / 4);   // n = 2^24, divisible by 4

    hipMemsetAsync(d_ws, 0, sizeof(float), stream);

    const int block = 256;
    const int rgrid = 4096;  // grid-stride: 1M threads, 4 vec-iters each
    reduce_change_kernel<<<rgrid, block, 0, stream>>>(f, nvec, n, sum_ws);

    int fgrid = (nvec + block - 1) / block;
    finalize_kernel<<<fgrid, block, 0, stream>>>(f, nvec, n, sum_ws, out);
}

// Round 3
// 128.448 us; speedup vs baseline: 1.2839x; 1.2839x over previous
//
#include <hip/hip_runtime.h>

// change[i] (i>=1) ∝ (g(i-3) - g(i+2))^2   with g(k)=f[k] zero-padded; change[0]=0
// out[i] = (1 - change[i]/S)^5 * f[i],  S = sum(change)
// The 1/5 conv scaling cancels in change[i]/S, so we accumulate unscaled d^2.

__device__ __forceinline__ float change_term(const float* __restrict__ f, long long i, long long n) {
    if (i < 1) return 0.0f;
    float a = (i >= 3)    ? f[i - 3] : 0.0f;
    float b = (i + 2 < n) ? f[i + 2] : 0.0f;
    float d = a - b;
    return d * d;
}

__device__ __forceinline__ float pow5(float t) {
    float t2 = t * t;
    float t4 = t2 * t2;
    return t4 * t;
}

__device__ __forceinline__ float vec_terms(float4 p, float4 c, float4 q) {
    // element j=4v+k: a=f[j-3], b=f[j+2]
    float d0 = p.y - c.z;
    float d1 = p.z - c.w;
    float d2 = p.w - q.x;
    float d3 = c.x - q.y;
    return d0 * d0 + d1 * d1 + d2 * d2 + d3 * d3;
}

__global__ void reduce_change_kernel(const float* __restrict__ f, int nvec, long long n,
                                     float* __restrict__ sum_out) {
    const float4* __restrict__ fv = (const float4*)f;
    const int T = gridDim.x * blockDim.x;
    const int tid = blockIdx.x * blockDim.x + threadIdx.x;
    const int M = nvec - 2;  // interior vectors: v = 1 + idx, idx in [0, M)
    float acc = 0.0f;

    int idx = tid;
    // unrolled-by-4 main loop: 12 independent float4 loads in flight
    for (; idx + 3 * T < M; idx += 4 * T) {
        float4 p[4], c[4], q[4];
        #pragma unroll
        for (int u = 0; u < 4; ++u) {
            int v = 1 + idx + u * T;
            p[u] = fv[v - 1];
            c[u] = fv[v];
            q[u] = fv[v + 1];
        }
        #pragma unroll
        for (int u = 0; u < 4; ++u)
            acc += vec_terms(p[u], c[u], q[u]);
    }
    // tail
    for (; idx < M; idx += T) {
        int v = 1 + idx;
        acc += vec_terms(fv[v - 1], fv[v], fv[v + 1]);
    }
    // edges: vectors v=0 and v=nvec-1, handled scalar by one thread
    if (tid == 0) {
        #pragma unroll
        for (int k = 0; k < 4; ++k) acc += change_term(f, k, n);
        long long j0 = n - 4;
        #pragma unroll
        for (int k = 0; k < 4; ++k) acc += change_term(f, j0 + k, n);
    }

    // wave (64-lane) reduction
    #pragma unroll
    for (int off = 32; off > 0; off >>= 1)
        acc += __shfl_down(acc, off, 64);
    __shared__ float smem[4];
    int lane = threadIdx.x & 63;
    int wave = threadIdx.x >> 6;
    if (lane == 0) smem[wave] = acc;
    __syncthreads();
    if (threadIdx.x == 0) {
        float s = smem[0] + smem[1] + smem[2] + smem[3];
        atomicAdd(sum_out, s);
    }
}

__device__ __forceinline__ float4 vec_out(float4 p, float4 c, float4 q, float inv) {
    float d0 = p.y - c.z;
    float d1 = p.z - c.w;
    float d2 = p.w - q.x;
    float d3 = c.x - q.y;
    float4 o;
    o.x = pow5(1.0f - d0 * d0 * inv) * c.x;
    o.y = pow5(1.0f - d1 * d1 * inv) * c.y;
    o.z = pow5(1.0f - d2 * d2 * inv) * c.z;
    o.w = pow5(1.0f - d3 * d3 * inv) * c.w;
    return o;
}

__global__ void finalize_kernel(const float* __restrict__ f, int nvec, long long n,
                                const float* __restrict__ sum_in,
                                float* __restrict__ out) {
    const float4* __restrict__ fv = (const float4*)f;
    float4* __restrict__ ov = (float4*)out;
    const int M = nvec - 2;       // interior vectors
    const int T = (M + 1) >> 1;   // each thread handles 2 strided interior vectors
    int tid = blockIdx.x * blockDim.x + threadIdx.x;
    if (tid < T) {
        int v1 = 1 + tid;
        bool has2 = (tid + T) < M;
        int v2 = has2 ? (1 + tid + T) : v1;
        // issue all 6 loads before compute
        float4 p1 = fv[v1 - 1], c1 = fv[v1], q1 = fv[v1 + 1];
        float4 p2 = fv[v2 - 1], c2 = fv[v2], q2 = fv[v2 + 1];
        float inv = 1.0f / *sum_in;
        ov[v1] = vec_out(p1, c1, q1, inv);
        if (has2) ov[v2] = vec_out(p2, c2, q2, inv);
    }
    if (tid == 0) {
        // edge vectors v=0 and v=nvec-1, scalar
        float inv = 1.0f / *sum_in;
        #pragma unroll
        for (int k = 0; k < 4; ++k) {
            float cge = change_term(f, k, n) * inv;
            out[k] = pow5(1.0f - cge) * f[k];
        }
        long long j0 = n - 4;
        #pragma unroll
        for (int k = 0; k < 4; ++k) {
            long long j = j0 + k;
            float cge = change_term(f, j, n) * inv;
            out[j] = pow5(1.0f - cge) * f[j];
        }
    }
}

extern "C" void kernel_launch(void* const* d_in, const int* in_sizes, int n_in,
                              void* d_out, int out_size, void* d_ws, size_t ws_size,
                              hipStream_t stream) {
    const float* f = (const float*)d_in[0];
    float* out = (float*)d_out;
    float* sum_ws = (float*)d_ws;
    long long n = (long long)in_sizes[0];
    int nvec = (int)(n / 4);  // n = 2^24, divisible by 4

    hipMemsetAsync(d_ws, 0, sizeof(float), stream);

    const int block = 256;
    reduce_change_kernel<<<1024, block, 0, stream>>>(f, nvec, n, sum_ws);

    int M = nvec - 2;
    int T = (M + 1) >> 1;
    int fgrid = (T + block - 1) / block;
    finalize_kernel<<<fgrid, block, 0, stream>>>(f, nvec, n, sum_ws, out);
}